// Round 5
// baseline (173.624 us; speedup 1.0000x reference)
//
#include <hip/hip_runtime.h>
#include <hip/hip_bf16.h>

// SE_loss_w_threshold: h,v (8,16384,128) fp32, N scalar.
// out[0]=mean(Rp), out[1..8]=R_per_user_p, out[9]=sum(R_per_user_p)

typedef float v2f __attribute__((ext_vector_type(2)));

constexpr int U_    = 8;
constexpr int B_    = 16384;
constexpr int NT_   = 128;
constexpr int D_    = 64;
constexpr int ROWP_ = 132;        // padded LDS row stride: A-loop reads conflict-free
constexpr int WPB_  = 4;          // waves per block
constexpr int NBLK_MAX = 4096;    // 1 sample per wave at full grid
constexpr float T_THRESH = 0.3f;
constexpr float LOG2_10  = 3.3219280948873623f;

// gfx950 hardware transcendentals: v_log_f32 computes log2(x), v_exp_f32 computes 2^x.
__device__ __forceinline__ float hw_log2(float x) { return __builtin_amdgcn_logf(x); }
__device__ __forceinline__ float hw_exp2(float x) { return __builtin_amdgcn_exp2f(x); }

__global__ __launch_bounds__(256, 4) void se_main(const float* __restrict__ h,
                                                  const float* __restrict__ vv,
                                                  const float* __restrict__ Np,
                                                  float* __restrict__ partial) {
    // Per-wave PRIVATE staging tile; no __syncthreads in the sample loop.
    __shared__ float lds[WPB_][2][U_ * ROWP_];
    __shared__ float red_f[WPB_];
    __shared__ float red_R[WPB_][U_];

    const int tid  = threadIdx.x;
    const int wave = tid >> 6;
    const int lane = tid & 63;
    const int ui   = lane >> 3;   // user i (row of A)
    const int uj   = lane & 7;    // user j (col of A)
    const float Nval = Np[0];

    float* hb = lds[wave][0];
    float* vb = lds[wave][1];

    float lane_sumR = 0.0f;
    float lane_sumf = 0.0f;

    const int gwave = blockIdx.x * WPB_ + wave;
    const int totw  = gridDim.x * WPB_;

    for (int b = gwave; b < B_; b += totw) {   // exactly 1 iter at full grid
        // ---- stage h,v rows for sample b into this wave's private tile ----
        v2f nsq2 = {0.0f, 0.0f};
        #pragma unroll
        for (int t = 0; t < 4; ++t) {
            const int idx = t * 64 + lane;
            const int row = idx >> 5;         // user row 0..7
            const int c4  = idx & 31;         // float4 index within row
            const size_t goff = (size_t)row * ((size_t)B_ * NT_) + (size_t)b * NT_ + (size_t)c4 * 4;
            const float4 h4 = *reinterpret_cast<const float4*>(h  + goff);
            const float4 v4 = *reinterpret_cast<const float4*>(vv + goff);
            *reinterpret_cast<float4*>(&hb[row * ROWP_ + c4 * 4]) = h4;
            *reinterpret_cast<float4*>(&vb[row * ROWP_ + c4 * 4]) = v4;
            const v2f va = {v4.x, v4.y}, vb2 = {v4.z, v4.w};
            nsq2 = __builtin_elementwise_fma(va,  va,  nsq2);
            nsq2 = __builtin_elementwise_fma(vb2, vb2, nsq2);
        }
        float nsq = nsq2[0] + nsq2[1];        // this lane's chunk of ||v||^2

        // ---- A[i][j] = sum_k h_c[i][k] * conj(v_c[j][k]) (packed fp32 FMA) ----
        v2f are2 = {0.0f, 0.0f}, aim2 = {0.0f, 0.0f};
        const float* hrow = &hb[ui * ROWP_];
        const float* vrow = &vb[uj * ROWP_];
        #pragma unroll
        for (int k = 0; k < D_; k += 4) {
            const float4 hr = *reinterpret_cast<const float4*>(hrow + k);
            const float4 hi = *reinterpret_cast<const float4*>(hrow + D_ + k);
            const float4 vr = *reinterpret_cast<const float4*>(vrow + k);
            const float4 vi = *reinterpret_cast<const float4*>(vrow + D_ + k);
            const v2f hra = {hr.x, hr.y}, hrb = {hr.z, hr.w};
            const v2f hia = {hi.x, hi.y}, hib = {hi.z, hi.w};
            const v2f vra = {vr.x, vr.y}, vrb = {vr.z, vr.w};
            const v2f via = {vi.x, vi.y}, vib = {vi.z, vi.w};
            are2 = __builtin_elementwise_fma(hra,  vra, are2);
            are2 = __builtin_elementwise_fma(hia,  via, are2);
            aim2 = __builtin_elementwise_fma(hia,  vra, aim2);
            aim2 = __builtin_elementwise_fma(-hra, via, aim2);
            are2 = __builtin_elementwise_fma(hrb,  vrb, are2);
            are2 = __builtin_elementwise_fma(hib,  vib, are2);
            aim2 = __builtin_elementwise_fma(hib,  vrb, aim2);
            aim2 = __builtin_elementwise_fma(-hrb, vib, aim2);
        }
        const float are  = are2[0] + are2[1];
        const float aim  = aim2[0] + aim2[1];
        const float Iall = are * are + aim * aim;

        // diag |A[i][i]|^2 broadcast within i-group (lane 9*i)
        const float diag = __shfl(Iall, ui * 9, 64);
        // row sum over j; ride nsq on the same first 3 steps, then finish it
        float rowsum = Iall;
        rowsum += __shfl_xor(rowsum, 1, 64);  nsq += __shfl_xor(nsq, 1, 64);
        rowsum += __shfl_xor(rowsum, 2, 64);  nsq += __shfl_xor(nsq, 2, 64);
        rowsum += __shfl_xor(rowsum, 4, 64);  nsq += __shfl_xor(nsq, 4, 64);
        nsq += __shfl_xor(nsq, 8,  64);
        nsq += __shfl_xor(nsq, 16, 64);
        nsq += __shfl_xor(nsq, 32, 64);       // now full ||v||^2, same in all lanes

        const float Ip   = rowsum - diag;              // interference (unscaled v)
        const float S    = (8.0f / nsq) * diag;        // scale^2 = num_user / ||v||^2
        const float SINR = S / (Ip + Nval);
        const float R    = hw_log2(1.0f + SINR);

        lane_sumR += R;                                       // per-user R (dup x8 per group)
        lane_sumf += hw_exp2((T_THRESH - R) * LOG2_10) - R;   // 10^(T-R) - R
    }

    // ---- block-level reduction (the only cross-wave communication) ----
    float wf = lane_sumf;
    #pragma unroll
    for (int m = 1; m < 64; m <<= 1) wf += __shfl_xor(wf, m, 64);
    wf *= 0.125f;                                      // each user counted 8x
    if (lane == 0) red_f[wave] = wf;
    if (uj == 0)   red_R[wave][ui] = lane_sumR;        // identical across j within group
    __syncthreads();

    if (tid < U_) {
        float s = 0.0f;
        #pragma unroll
        for (int w = 0; w < WPB_; ++w) s += red_R[w][tid];
        partial[blockIdx.x * 9 + 1 + tid] = s;
    } else if (tid == U_) {
        float s = 0.0f;
        #pragma unroll
        for (int w = 0; w < WPB_; ++w) s += red_f[w];
        partial[blockIdx.x * 9] = s;
    }
}

__global__ __launch_bounds__(256) void se_final(const float* __restrict__ partial,
                                                float* __restrict__ out, int nblk) {
    __shared__ float sums[9];
    if (threadIdx.x < 9) sums[threadIdx.x] = 0.0f;
    __syncthreads();

    float local[9];
    #pragma unroll
    for (int s = 0; s < 9; ++s) local[s] = 0.0f;
    for (int b = threadIdx.x; b < nblk; b += 256) {
        #pragma unroll
        for (int s = 0; s < 9; ++s) local[s] += partial[b * 9 + s];
    }
    #pragma unroll
    for (int s = 0; s < 9; ++s) atomicAdd(&sums[s], local[s]);
    __syncthreads();

    if (threadIdx.x == 0) {
        const float inv = 1.0f / (float)B_;
        out[0] = sums[0] * inv;          // mean(Rp)
        float tot = 0.0f;
        #pragma unroll
        for (int i = 0; i < U_; ++i) {
            const float r = sums[1 + i] * inv;
            out[1 + i] = r;              // R_per_user_p
            tot += r;
        }
        out[9] = tot;                    // sum(R_per_user_p)
    }
}

extern "C" void kernel_launch(void* const* d_in, const int* in_sizes, int n_in,
                              void* d_out, int out_size, void* d_ws, size_t ws_size,
                              hipStream_t stream) {
    const float* h  = (const float*)d_in[0];
    const float* v  = (const float*)d_in[1];
    const float* Np = (const float*)d_in[2];
    float* out      = (float*)d_out;
    float* partial  = (float*)d_ws;

    int nblk = NBLK_MAX;
    const size_t need = (size_t)NBLK_MAX * 9 * sizeof(float);
    if (ws_size < need) {                      // ws_size is fixed per process -> deterministic
        nblk = (int)(ws_size / (9 * sizeof(float)));
        if (nblk < 1) nblk = 1;
    }

    se_main<<<nblk, 256, 0, stream>>>(h, v, Np, partial);
    se_final<<<1, 256, 0, stream>>>(partial, out, nblk);
}

// Round 7
// 172.128 us; speedup vs baseline: 1.0087x; 1.0087x over previous
//
#include <hip/hip_runtime.h>
#include <hip/hip_bf16.h>

// SE_loss_w_threshold: h,v (8,16384,128) fp32, N scalar.
// out[0]=mean(Rp), out[1..8]=R_per_user_p, out[9]=sum(R_per_user_p)

typedef float v2f __attribute__((ext_vector_type(2)));
typedef _Float16 h2  __attribute__((ext_vector_type(2)));
typedef _Float16 h4  __attribute__((ext_vector_type(4)));

struct alignas(16) h2x4 { h2 a, b, c, d; };   // one ds_read_b128 worth of fp16 pairs

constexpr int U_    = 8;
constexpr int B_    = 16384;
constexpr int NT_   = 128;
constexpr int ROWH_ = 136;        // halfs per LDS row (272 B, 16B-aligned rows)
constexpr int WPB_  = 4;          // waves per block
constexpr int NBLK_MAX = 4096;    // 1 sample per wave at full grid
constexpr float T_THRESH = 0.3f;
constexpr float LOG2_10  = 3.3219280948873623f;

// gfx950 hardware transcendentals: v_log_f32 computes log2(x), v_exp_f32 computes 2^x.
__device__ __forceinline__ float hw_log2(float x) { return __builtin_amdgcn_logf(x); }
__device__ __forceinline__ float hw_exp2(float x) { return __builtin_amdgcn_exp2f(x); }

__global__ __launch_bounds__(256, 4) void se_main(const float* __restrict__ h,
                                                  const float* __restrict__ vv,
                                                  const float* __restrict__ Np,
                                                  float* __restrict__ partial) {
    // Per-wave PRIVATE fp16 staging tile (17.4 KB/block -> 8 blocks/CU = full occupancy).
    // No __syncthreads in the sample loop; same-wave ds ordering via lgkmcnt.
    __shared__ alignas(16) _Float16 lds[WPB_][2][U_ * ROWH_];
    __shared__ float red_f[WPB_];
    __shared__ float red_R[WPB_][U_];

    const int tid  = threadIdx.x;
    const int wave = tid >> 6;
    const int lane = tid & 63;
    const int ui   = lane >> 3;   // user i (row of A)
    const int uj   = lane & 7;    // user j (col of A)
    const float Nval = Np[0];

    _Float16* hb = lds[wave][0];
    _Float16* vb = lds[wave][1];

    float lane_sumR = 0.0f;
    float lane_sumf = 0.0f;

    const int gwave = blockIdx.x * WPB_ + wave;
    const int totw  = gridDim.x * WPB_;

    for (int b = gwave; b < B_; b += totw) {   // exactly 1 iter at full grid
        // ---- stage h,v rows for sample b into fp16 LDS tile ----
        v2f nsq2 = {0.0f, 0.0f};
        #pragma unroll
        for (int t = 0; t < 4; ++t) {
            const int idx = t * 64 + lane;
            const int row = idx >> 5;         // user row 0..7
            const int c4  = idx & 31;         // float4 index within row
            const size_t goff = (size_t)row * ((size_t)B_ * NT_) + (size_t)b * NT_ + (size_t)c4 * 4;
            const float4 h4f = *reinterpret_cast<const float4*>(h  + goff);
            const float4 v4f = *reinterpret_cast<const float4*>(vv + goff);
            // norm from exact fp32 values
            const v2f va = {v4f.x, v4f.y}, vbp = {v4f.z, v4f.w};
            nsq2 = __builtin_elementwise_fma(va,  va,  nsq2);
            nsq2 = __builtin_elementwise_fma(vbp, vbp, nsq2);
            // RNE convert to fp16 and store 8B per array
            h4 hh = { (_Float16)h4f.x, (_Float16)h4f.y, (_Float16)h4f.z, (_Float16)h4f.w };
            h4 vh = { (_Float16)v4f.x, (_Float16)v4f.y, (_Float16)v4f.z, (_Float16)v4f.w };
            *reinterpret_cast<h4*>(&hb[row * ROWH_ + c4 * 4]) = hh;
            *reinterpret_cast<h4*>(&vb[row * ROWH_ + c4 * 4]) = vh;
        }
        float nsq = nsq2[0] + nsq2[1];        // this lane's chunk of ||v||^2

        // ---- A[i][j] = sum_k h_c[i][k] * conj(v_c[j][k]) via v_dot2_f32_f16 ----
        // 4 positive-accumulate chains: t1=hr.vr t2=hi.vi t3=hi.vr t4=hr.vi
        float t1 = 0.0f, t2 = 0.0f, t3 = 0.0f, t4 = 0.0f;
        const _Float16* hrow = &hb[ui * ROWH_];
        const _Float16* vrow = &vb[uj * ROWH_];
        #pragma unroll
        for (int c = 0; c < 8; ++c) {
            const h2x4 hre = *reinterpret_cast<const h2x4*>(hrow + c * 8);
            const h2x4 him = *reinterpret_cast<const h2x4*>(hrow + 64 + c * 8);
            const h2x4 vre = *reinterpret_cast<const h2x4*>(vrow + c * 8);
            const h2x4 vim = *reinterpret_cast<const h2x4*>(vrow + 64 + c * 8);
            t1 = __builtin_amdgcn_fdot2(hre.a, vre.a, t1, false);
            t2 = __builtin_amdgcn_fdot2(him.a, vim.a, t2, false);
            t3 = __builtin_amdgcn_fdot2(him.a, vre.a, t3, false);
            t4 = __builtin_amdgcn_fdot2(hre.a, vim.a, t4, false);
            t1 = __builtin_amdgcn_fdot2(hre.b, vre.b, t1, false);
            t2 = __builtin_amdgcn_fdot2(him.b, vim.b, t2, false);
            t3 = __builtin_amdgcn_fdot2(him.b, vre.b, t3, false);
            t4 = __builtin_amdgcn_fdot2(hre.b, vim.b, t4, false);
            t1 = __builtin_amdgcn_fdot2(hre.c, vre.c, t1, false);
            t2 = __builtin_amdgcn_fdot2(him.c, vim.c, t2, false);
            t3 = __builtin_amdgcn_fdot2(him.c, vre.c, t3, false);
            t4 = __builtin_amdgcn_fdot2(hre.c, vim.c, t4, false);
            t1 = __builtin_amdgcn_fdot2(hre.d, vre.d, t1, false);
            t2 = __builtin_amdgcn_fdot2(him.d, vim.d, t2, false);
            t3 = __builtin_amdgcn_fdot2(him.d, vre.d, t3, false);
            t4 = __builtin_amdgcn_fdot2(hre.d, vim.d, t4, false);
        }
        const float are  = t1 + t2;
        const float aim  = t3 - t4;
        const float Iall = are * are + aim * aim;

        // diag |A[i][i]|^2 broadcast within i-group (lane 9*i)
        const float diag = __shfl(Iall, ui * 9, 64);
        // row sum over j; ride nsq on the same first 3 steps, then finish it
        float rowsum = Iall;
        rowsum += __shfl_xor(rowsum, 1, 64);  nsq += __shfl_xor(nsq, 1, 64);
        rowsum += __shfl_xor(rowsum, 2, 64);  nsq += __shfl_xor(nsq, 2, 64);
        rowsum += __shfl_xor(rowsum, 4, 64);  nsq += __shfl_xor(nsq, 4, 64);
        nsq += __shfl_xor(nsq, 8,  64);
        nsq += __shfl_xor(nsq, 16, 64);
        nsq += __shfl_xor(nsq, 32, 64);       // now full ||v||^2, same in all lanes

        const float Ip   = rowsum - diag;              // interference (unscaled v)
        const float S    = (8.0f / nsq) * diag;        // scale^2 = num_user / ||v||^2
        const float SINR = S / (Ip + Nval);
        const float R    = hw_log2(1.0f + SINR);

        lane_sumR += R;                                       // per-user R (dup x8 per group)
        lane_sumf += hw_exp2((T_THRESH - R) * LOG2_10) - R;   // 10^(T-R) - R
    }

    // ---- block-level reduction (the only cross-wave communication) ----
    float wf = lane_sumf;
    #pragma unroll
    for (int m = 1; m < 64; m <<= 1) wf += __shfl_xor(wf, m, 64);
    wf *= 0.125f;                                      // each user counted 8x
    if (lane == 0) red_f[wave] = wf;
    if (uj == 0)   red_R[wave][ui] = lane_sumR;        // identical across j within group
    __syncthreads();

    if (tid < U_) {
        float s = 0.0f;
        #pragma unroll
        for (int w = 0; w < WPB_; ++w) s += red_R[w][tid];
        partial[blockIdx.x * 9 + 1 + tid] = s;
    } else if (tid == U_) {
        float s = 0.0f;
        #pragma unroll
        for (int w = 0; w < WPB_; ++w) s += red_f[w];
        partial[blockIdx.x * 9] = s;
    }
}

__global__ __launch_bounds__(256) void se_final(const float* __restrict__ partial,
                                                float* __restrict__ out, int nblk) {
    __shared__ float sums[9];
    if (threadIdx.x < 9) sums[threadIdx.x] = 0.0f;
    __syncthreads();

    float local[9];
    #pragma unroll
    for (int s = 0; s < 9; ++s) local[s] = 0.0f;
    for (int b = threadIdx.x; b < nblk; b += 256) {
        #pragma unroll
        for (int s = 0; s < 9; ++s) local[s] += partial[b * 9 + s];
    }
    #pragma unroll
    for (int s = 0; s < 9; ++s) atomicAdd(&sums[s], local[s]);
    __syncthreads();

    if (threadIdx.x == 0) {
        const float inv = 1.0f / (float)B_;
        out[0] = sums[0] * inv;          // mean(Rp)
        float tot = 0.0f;
        #pragma unroll
        for (int i = 0; i < U_; ++i) {
            const float r = sums[1 + i] * inv;
            out[1 + i] = r;              // R_per_user_p
            tot += r;
        }
        out[9] = tot;                    // sum(R_per_user_p)
    }
}

extern "C" void kernel_launch(void* const* d_in, const int* in_sizes, int n_in,
                              void* d_out, int out_size, void* d_ws, size_t ws_size,
                              hipStream_t stream) {
    const float* h  = (const float*)d_in[0];
    const float* v  = (const float*)d_in[1];
    const float* Np = (const float*)d_in[2];
    float* out      = (float*)d_out;
    float* partial  = (float*)d_ws;

    int nblk = NBLK_MAX;
    const size_t need = (size_t)NBLK_MAX * 9 * sizeof(float);
    if (ws_size < need) {                      // ws_size is fixed per process -> deterministic
        nblk = (int)(ws_size / (9 * sizeof(float)));
        if (nblk < 1) nblk = 1;
    }

    se_main<<<nblk, 256, 0, stream>>>(h, v, Np, partial);
    se_final<<<1, 256, 0, stream>>>(partial, out, nblk);
}